// Round 8
// baseline (573.914 us; speedup 1.0000x reference)
//
#include <hip/hip_runtime.h>

typedef _Float16 f16x8 __attribute__((ext_vector_type(8)));
typedef float f32x4 __attribute__((ext_vector_type(4)));

// ---------------------------------------------------------------------------
// DeformConv stack: 8 layers, N=4, H=W=64.
// L0 (512->256, k=1), L1 (256->128, 3x3), L2..L7 (128->128, 3x3)
// Round-6 proven core (4 waves, 64px x 128co, stride-40 LDS, fp16 hi/lo
// 3-term MFMA, XCD swizzle) + two scheduling-only changes:
//  1) counted barrier: s_waitcnt lgkmcnt(0); s_barrier  (globals NOT drained
//     -- inter-wave comms are LDS-only; per-reg vmcnt waits auto-inserted)
//  2) depth-2 prefetch: loads for iteration i+2 issued at iteration i,
//     double register sets (statically indexed), coefs snapshot per set.
// Values and MFMA accumulation order identical to round 6.
// ---------------------------------------------------------------------------

__global__ __launch_bounds__(256) void nchw2nhwc(const float* __restrict__ in,
                                                 float* __restrict__ out, int C) {
    const int ctiles = C >> 5;
    const int ct = blockIdx.x % ctiles;
    const int xt = blockIdx.x / ctiles;
    const int y = blockIdx.y, n = blockIdx.z;
    const int c0 = ct * 32, x0 = xt * 32;
    __shared__ float tile[32][33];
    const int tx = threadIdx.x & 31, tr = threadIdx.x >> 5;
#pragma unroll
    for (int r = 0; r < 32; r += 8) {
        const int c = c0 + tr + r;
        tile[tr + r][tx] = in[(((n * C + c) << 6) + y) * 64 + x0 + tx];
    }
    __syncthreads();
#pragma unroll
    for (int r = 0; r < 32; r += 8) {
        const int x = x0 + tr + r;
        out[((((n << 6) + y) * 64) + x) * C + c0 + tx] = tile[tx][tr + r];
    }
}

__global__ __launch_bounds__(256) void nhwc2nchw(const float* __restrict__ in,
                                                 float* __restrict__ out, int C) {
    const int ctiles = C >> 5;
    const int ct = blockIdx.x % ctiles;
    const int xt = blockIdx.x / ctiles;
    const int y = blockIdx.y, n = blockIdx.z;
    const int c0 = ct * 32, x0 = xt * 32;
    __shared__ float tile[32][33];
    const int tx = threadIdx.x & 31, tr = threadIdx.x >> 5;
#pragma unroll
    for (int r = 0; r < 32; r += 8) {
        const int x = x0 + tr + r;
        tile[tr + r][tx] = in[((((n << 6) + y) * 64) + x) * C + c0 + tx];
    }
    __syncthreads();
#pragma unroll
    for (int r = 0; r < 32; r += 8) {
        const int c = c0 + tr + r;
        out[(((n * C + c) << 6) + y) * 64 + x0 + tx] = tile[tx][tr + r];
    }
}

// w[cout][cin][kh][kw] fp32 -> wt rows of 64 halves: [k][chunk][co][ hi(32) | lo(32) ]
__global__ __launch_bounds__(256) void prep_w(const float* __restrict__ w,
                                              _Float16* __restrict__ wt,
                                              int CIN, int COUT, int KK, int total) {
    const int idx = blockIdx.x * 256 + threadIdx.x;
    if (idx >= total) return;
    const int e = idx & 31;
    int r = idx >> 5;
    const int co = r % COUT;
    r /= COUT;
    const int nc = CIN >> 5;
    const int c = r % nc;
    const int k = r / nc;
    const int ci = c * 32 + e;
    const float v = w[(co * CIN + ci) * KK + k];
    const _Float16 h = (_Float16)v;
    const _Float16 l = (_Float16)(v - (float)h);
    const size_t row = ((size_t)(k * nc + c) * COUT + co) * 64;
    wt[row + e] = h;
    wt[row + 32 + e] = l;
}

struct Set {
    float4 a[8];   // 4 corners x 8 channels
    uint4 b[4];    // B hi (2x16B) + lo (2x16B)
    float w[4];    // bilinear coefs snapshot
};

// Deformable conv layer. grid: (256, COUTF/128), block 256 (4 waves).
// Block tile: 64 px (one image row) x 128 couts. Wave: 32 px x 64 co.
template <int TAPS, int CIN, int COUTF>
__global__ __launch_bounds__(256) void dconv_mfma(const float* __restrict__ in,
                                                  const float* __restrict__ off,
                                                  const _Float16* __restrict__ wt,
                                                  const float* __restrict__ bias,
                                                  float* __restrict__ out) {
    constexpr int KS = (TAPS == 9) ? 3 : 1;
    constexpr int PAD = (TAPS == 9) ? 1 : 0;
    constexpr int NC = CIN / 32;          // 32-channel chunks (NC >= 4 always)
    constexpr int TOTAL_IT = TAPS * NC;   // even: 16, 72, 36

    __shared__ __align__(16) _Float16 sAh[64 * 40];
    __shared__ __align__(16) _Float16 sAl[64 * 40];
    __shared__ __align__(16) _Float16 sBh[128 * 40];
    __shared__ __align__(16) _Float16 sBl[128 * 40];

    const int t = threadIdx.x;
    const int bx0 = blockIdx.x;
    const int bx = (bx0 & 7) * 32 + (bx0 >> 3); // bijective XCD swizzle
    const int coy = blockIdx.y;
    const int n = bx >> 6, y = bx & 63;

    // staging roles
    const int px = t & 63;
    const int cg = t >> 6;         // 8-ci group (0..3)
    const int bco = t >> 1;        // B row 0..127
    const int bh = t & 1;

    // mfma roles
    const int lane = t & 63, wv = t >> 6;
    const int wm = wv & 1, wn = wv >> 1;
    const int l15 = lane & 15, lq = lane >> 4;

    // tap pointer-state (updated by mkcoef)
    float wl0, wl1, wl2, wl3;
    const float *p00, *p01, *p10, *p11;

    auto mkcoef = [&](int k, float dy, float dx) {
        const int kh = k / KS, kw = k - kh * KS;
        const float py = (float)(y + kh - PAD) + dy;
        const float pxc = (float)(px + kw - PAD) + dx;
        const float y0f = floorf(py), x0f = floorf(pxc);
        const int iy0 = (int)y0f, ix0 = (int)x0f;
        const int iy1 = iy0 + 1, ix1 = ix0 + 1;
        const float wy1 = py - y0f, wy0 = 1.f - wy1;
        const float wx1 = pxc - x0f, wx0 = 1.f - wx1;
        const bool vy0 = (iy0 >= 0) & (iy0 < 64), vy1 = (iy1 >= 0) & (iy1 < 64);
        const bool vx0 = (ix0 >= 0) & (ix0 < 64), vx1 = (ix1 >= 0) & (ix1 < 64);
        wl0 = (vy0 & vx0) ? wy0 * wx0 : 0.f;
        wl1 = (vy0 & vx1) ? wy0 * wx1 : 0.f;
        wl2 = (vy1 & vx0) ? wy1 * wx0 : 0.f;
        wl3 = (vy1 & vx1) ? wy1 * wx1 : 0.f;
        const int cy0 = min(max(iy0, 0), 63), cy1 = min(max(iy1, 0), 63);
        const int cx0 = min(max(ix0, 0), 63), cx1 = min(max(ix1, 0), 63);
        p00 = in + (size_t)(((n << 6) + cy0) * 64 + cx0) * CIN + cg * 8;
        p01 = in + (size_t)(((n << 6) + cy0) * 64 + cx1) * CIN + cg * 8;
        p10 = in + (size_t)(((n << 6) + cy1) * 64 + cx0) * CIN + cg * 8;
        p11 = in + (size_t)(((n << 6) + cy1) * 64 + cx1) * CIN + cg * 8;
    };

    auto oidx = [&](int k) { return ((n * 2 * TAPS + 2 * k) * 64 + y) * 64 + px; };

    auto load_into = [&](Set& s, int k, int c) {
        const float* q0 = p00 + c * 32;
        const float* q1 = p01 + c * 32;
        const float* q2 = p10 + c * 32;
        const float* q3 = p11 + c * 32;
        s.a[0] = *(const float4*)q0; s.a[1] = *(const float4*)(q0 + 4);
        s.a[2] = *(const float4*)q1; s.a[3] = *(const float4*)(q1 + 4);
        s.a[4] = *(const float4*)q2; s.a[5] = *(const float4*)(q2 + 4);
        s.a[6] = *(const float4*)q3; s.a[7] = *(const float4*)(q3 + 4);
        const size_t brow = ((size_t)(k * NC + c) * COUTF + coy * 128 + bco) * 64;
        const uint4* bp = (const uint4*)(wt + brow);
        s.b[0] = bp[bh * 2]; s.b[1] = bp[bh * 2 + 1];
        s.b[2] = bp[4 + bh * 2]; s.b[3] = bp[5 + bh * 2];
        s.w[0] = wl0; s.w[1] = wl1; s.w[2] = wl2; s.w[3] = wl3;
    };

    auto write_chunk = [&](const Set& s) {
        float v[8];
        v[0] = s.w[0] * s.a[0].x + s.w[1] * s.a[2].x + s.w[2] * s.a[4].x + s.w[3] * s.a[6].x;
        v[1] = s.w[0] * s.a[0].y + s.w[1] * s.a[2].y + s.w[2] * s.a[4].y + s.w[3] * s.a[6].y;
        v[2] = s.w[0] * s.a[0].z + s.w[1] * s.a[2].z + s.w[2] * s.a[4].z + s.w[3] * s.a[6].z;
        v[3] = s.w[0] * s.a[0].w + s.w[1] * s.a[2].w + s.w[2] * s.a[4].w + s.w[3] * s.a[6].w;
        v[4] = s.w[0] * s.a[1].x + s.w[1] * s.a[3].x + s.w[2] * s.a[5].x + s.w[3] * s.a[7].x;
        v[5] = s.w[0] * s.a[1].y + s.w[1] * s.a[3].y + s.w[2] * s.a[5].y + s.w[3] * s.a[7].y;
        v[6] = s.w[0] * s.a[1].z + s.w[1] * s.a[3].z + s.w[2] * s.a[5].z + s.w[3] * s.a[7].z;
        v[7] = s.w[0] * s.a[1].w + s.w[1] * s.a[3].w + s.w[2] * s.a[5].w + s.w[3] * s.a[7].w;
        f16x8 hv, lv;
#pragma unroll
        for (int j = 0; j < 8; ++j) {
            const _Float16 h = (_Float16)v[j];
            hv[j] = h;
            lv[j] = (_Float16)(v[j] - (float)h);
        }
        *(f16x8*)&sAh[px * 40 + cg * 8] = hv;
        *(f16x8*)&sAl[px * 40 + cg * 8] = lv;
        *(uint4*)&sBh[bco * 40 + bh * 16] = s.b[0];
        *(uint4*)&sBh[bco * 40 + bh * 16 + 8] = s.b[1];
        *(uint4*)&sBl[bco * 40 + bh * 16] = s.b[2];
        *(uint4*)&sBl[bco * 40 + bh * 16 + 8] = s.b[3];
    };

    // LDS-only barrier: ds ops drained, global loads stay in flight (T4).
    auto bar = [] { asm volatile("s_waitcnt lgkmcnt(0)\n\ts_barrier" ::: "memory"); };

    // prologue: issue loads for it=0 and it=1 (same tap 0 since NC>=4)
    mkcoef(0, off[oidx(0)], off[oidx(0) + 4096]);
    float dyn = 0.f, dxn = 0.f;
    if (TAPS > 1) { dyn = off[oidx(1)]; dxn = off[oidx(1) + 4096]; }
    Set s0, s1;
    load_into(s0, 0, 0);
    load_into(s1, 0, 1);
    int kq = 0, cq = 1;   // indices of last issued load

    f32x4 acc[2][4] = {};

    auto body = [&](Set& scur, int it) {
        bar();                         // previous MFMA done reading LDS
        write_chunk(scur);             // consume set (vmcnt waits auto-inserted)
        if (it + 2 < TOTAL_IT) {       // issue loads for it+2 into freed set
            int c2 = cq + 1, k2 = kq;
            if (c2 == NC) {
                c2 = 0; k2 = kq + 1;
                mkcoef(k2, dyn, dxn);
                if (k2 + 1 < TAPS) { dyn = off[oidx(k2 + 1)]; dxn = off[oidx(k2 + 1) + 4096]; }
            }
            load_into(scur, k2, c2);
            kq = k2; cq = c2;
        }
        bar();                         // staged data visible

        f16x8 ah[2], al[2], bhv[4], blv[4];
#pragma unroll
        for (int mi = 0; mi < 2; ++mi) {
            const int ar = wm * 32 + mi * 16 + l15;
            ah[mi] = *(const f16x8*)&sAh[ar * 40 + lq * 8];
            al[mi] = *(const f16x8*)&sAl[ar * 40 + lq * 8];
        }
#pragma unroll
        for (int ni = 0; ni < 4; ++ni) {
            const int br = wn * 64 + ni * 16 + l15;
            bhv[ni] = *(const f16x8*)&sBh[br * 40 + lq * 8];
            blv[ni] = *(const f16x8*)&sBl[br * 40 + lq * 8];
        }
#pragma unroll
        for (int mi = 0; mi < 2; ++mi)
#pragma unroll
            for (int ni = 0; ni < 4; ++ni) {
                acc[mi][ni] = __builtin_amdgcn_mfma_f32_16x16x32_f16(ah[mi], bhv[ni], acc[mi][ni], 0, 0, 0);
                acc[mi][ni] = __builtin_amdgcn_mfma_f32_16x16x32_f16(ah[mi], blv[ni], acc[mi][ni], 0, 0, 0);
                acc[mi][ni] = __builtin_amdgcn_mfma_f32_16x16x32_f16(al[mi], bhv[ni], acc[mi][ni], 0, 0, 0);
            }
    };

    for (int it = 0; it < TOTAL_IT; it += 2) {
        body(s0, it);
        body(s1, it + 1);
    }

    // epilogue: bias + ReLU, fp32 NHWC store
    const size_t pixbase = (size_t)bx * 64;
#pragma unroll
    for (int ni = 0; ni < 4; ++ni) {
        const int co = coy * 128 + wn * 64 + ni * 16 + l15;
        const float bv = bias[co];
#pragma unroll
        for (int mi = 0; mi < 2; ++mi) {
#pragma unroll
            for (int r = 0; r < 4; ++r) {
                const int pxl = wm * 32 + mi * 16 + lq * 4 + r;
                out[(pixbase + pxl) * COUTF + co] = fmaxf(acc[mi][ni][r] + bv, 0.f);
            }
        }
    }
}

extern "C" void kernel_launch(void* const* d_in, const int* in_sizes, int n_in,
                              void* d_out, int out_size, void* d_ws, size_t ws_size,
                              hipStream_t stream) {
    (void)in_sizes; (void)n_in; (void)out_size; (void)ws_size;
    const float* x = (const float*)d_in[0];
    const float* offs[8];
    const float* wsrc[8];
    const float* bs[8];
    for (int i = 0; i < 8; ++i) {
        offs[i] = (const float*)d_in[1 + i];
        wsrc[i] = (const float*)d_in[9 + 2 * i];
        bs[i] = (const float*)d_in[10 + 2 * i];
    }
    float* bufA = (float*)d_ws;                                  // 32 MB
    float* bufB = (float*)((char*)d_ws + 33554432u);             // 16 MB
    _Float16* wt = (_Float16*)((char*)d_ws + 50331648u);         // 5.25 MB
    const size_t wo[8] = {0, 262144, 851968, 1146880, 1441792, 1736704, 2031616, 2326528};
    const int cins[8] = {512, 256, 128, 128, 128, 128, 128, 128};
    const int couts[8] = {256, 128, 128, 128, 128, 128, 128, 128};
    const int kks[8] = {1, 9, 9, 9, 9, 9, 9, 9};

    nchw2nhwc<<<dim3((512 / 32) * 2, 64, 4), 256, 0, stream>>>(x, bufA, 512);
    for (int i = 0; i < 8; ++i) {
        const int total = kks[i] * cins[i] * couts[i];
        prep_w<<<(total + 255) / 256, 256, 0, stream>>>(wsrc[i], wt + wo[i],
                                                        cins[i], couts[i], kks[i], total);
    }
    dconv_mfma<1, 512, 256><<<dim3(256, 2), 256, 0, stream>>>(bufA, offs[0], wt + wo[0], bs[0], bufB);
    dconv_mfma<9, 256, 128><<<dim3(256, 1), 256, 0, stream>>>(bufB, offs[1], wt + wo[1], bs[1], bufA);
    dconv_mfma<9, 128, 128><<<dim3(256, 1), 256, 0, stream>>>(bufA, offs[2], wt + wo[2], bs[2], bufB);
    dconv_mfma<9, 128, 128><<<dim3(256, 1), 256, 0, stream>>>(bufB, offs[3], wt + wo[3], bs[3], bufA);
    dconv_mfma<9, 128, 128><<<dim3(256, 1), 256, 0, stream>>>(bufA, offs[4], wt + wo[4], bs[4], bufB);
    dconv_mfma<9, 128, 128><<<dim3(256, 1), 256, 0, stream>>>(bufB, offs[5], wt + wo[5], bs[5], bufA);
    dconv_mfma<9, 128, 128><<<dim3(256, 1), 256, 0, stream>>>(bufA, offs[6], wt + wo[6], bs[6], bufB);
    dconv_mfma<9, 128, 128><<<dim3(256, 1), 256, 0, stream>>>(bufB, offs[7], wt + wo[7], bs[7], bufA);
    nhwc2nchw<<<dim3((128 / 32) * 2, 64, 4), 256, 0, stream>>>(bufA, (float*)d_out, 128);
}

// Round 9
// 393.677 us; speedup vs baseline: 1.4578x; 1.4578x over previous
//
#include <hip/hip_runtime.h>

typedef _Float16 f16x8 __attribute__((ext_vector_type(8)));
typedef _Float16 f16x4 __attribute__((ext_vector_type(4)));
typedef float f32x4 __attribute__((ext_vector_type(4)));

// ---------------------------------------------------------------------------
// DeformConv stack: 8 layers, N=4, H=W=64.
// L0 (512->256, k=1), L1 (256->128, 3x3), L2..L7 (128->128, 3x3)
// Round-6 proven core (4 waves, 64px x 128co tile, stride-40 LDS, fp16 hi/lo
// 3-term MFMA, XCD swizzle, two-barrier depth-1 prefetch) with ONE change:
// COALESCED A-GATHER. Staging thread role is now (pixel p = t>>3, ch-quad
// j = t&7, slots p and p+32): 8 consecutive lanes read 8 consecutive float4
// of the same pixel-corner -> each load instruction touches 8 contiguous
// 128B segments (~8 L2 requests) instead of 64 scattered ones. Same bytes,
// same instruction count, same arithmetic -> same output values.
// ---------------------------------------------------------------------------

__global__ __launch_bounds__(256) void nchw2nhwc(const float* __restrict__ in,
                                                 float* __restrict__ out, int C) {
    const int ctiles = C >> 5;
    const int ct = blockIdx.x % ctiles;
    const int xt = blockIdx.x / ctiles;
    const int y = blockIdx.y, n = blockIdx.z;
    const int c0 = ct * 32, x0 = xt * 32;
    __shared__ float tile[32][33];
    const int tx = threadIdx.x & 31, tr = threadIdx.x >> 5;
#pragma unroll
    for (int r = 0; r < 32; r += 8) {
        const int c = c0 + tr + r;
        tile[tr + r][tx] = in[(((n * C + c) << 6) + y) * 64 + x0 + tx];
    }
    __syncthreads();
#pragma unroll
    for (int r = 0; r < 32; r += 8) {
        const int x = x0 + tr + r;
        out[((((n << 6) + y) * 64) + x) * C + c0 + tx] = tile[tx][tr + r];
    }
}

__global__ __launch_bounds__(256) void nhwc2nchw(const float* __restrict__ in,
                                                 float* __restrict__ out, int C) {
    const int ctiles = C >> 5;
    const int ct = blockIdx.x % ctiles;
    const int xt = blockIdx.x / ctiles;
    const int y = blockIdx.y, n = blockIdx.z;
    const int c0 = ct * 32, x0 = xt * 32;
    __shared__ float tile[32][33];
    const int tx = threadIdx.x & 31, tr = threadIdx.x >> 5;
#pragma unroll
    for (int r = 0; r < 32; r += 8) {
        const int x = x0 + tr + r;
        tile[tr + r][tx] = in[((((n << 6) + y) * 64) + x) * C + c0 + tx];
    }
    __syncthreads();
#pragma unroll
    for (int r = 0; r < 32; r += 8) {
        const int c = c0 + tr + r;
        out[(((n * C + c) << 6) + y) * 64 + x0 + tx] = tile[tx][tr + r];
    }
}

// w[cout][cin][kh][kw] fp32 -> wt rows of 64 halves: [k][chunk][co][ hi(32) | lo(32) ]
__global__ __launch_bounds__(256) void prep_w(const float* __restrict__ w,
                                              _Float16* __restrict__ wt,
                                              int CIN, int COUT, int KK, int total) {
    const int idx = blockIdx.x * 256 + threadIdx.x;
    if (idx >= total) return;
    const int e = idx & 31;
    int r = idx >> 5;
    const int co = r % COUT;
    r /= COUT;
    const int nc = CIN >> 5;
    const int c = r % nc;
    const int k = r / nc;
    const int ci = c * 32 + e;
    const float v = w[(co * CIN + ci) * KK + k];
    const _Float16 h = (_Float16)v;
    const _Float16 l = (_Float16)(v - (float)h);
    const size_t row = ((size_t)(k * nc + c) * COUT + co) * 64;
    wt[row + e] = h;
    wt[row + 32 + e] = l;
}

struct PixSt {
    float w0, w1, w2, w3;
    const float *p00, *p01, *p10, *p11;
};

// Deformable conv layer. grid: (256, COUTF/128), block 256 (4 waves).
// Block tile: 64 px (one image row) x 128 couts. Wave: 32 px x 64 co.
template <int TAPS, int CIN, int COUTF>
__global__ __launch_bounds__(256) void dconv_mfma(const float* __restrict__ in,
                                                  const float* __restrict__ off,
                                                  const _Float16* __restrict__ wt,
                                                  const float* __restrict__ bias,
                                                  float* __restrict__ out) {
    constexpr int KS = (TAPS == 9) ? 3 : 1;
    constexpr int PAD = (TAPS == 9) ? 1 : 0;
    constexpr int NC = CIN / 32;          // 32-channel chunks
    constexpr int TOTAL_IT = TAPS * NC;

    // padded tiles: stride 40 halves (80 B)
    __shared__ __align__(16) _Float16 sAh[64 * 40];
    __shared__ __align__(16) _Float16 sAl[64 * 40];
    __shared__ __align__(16) _Float16 sBh[128 * 40];
    __shared__ __align__(16) _Float16 sBl[128 * 40];

    const int t = threadIdx.x;
    const int bx0 = blockIdx.x;
    const int bx = (bx0 & 7) * 32 + (bx0 >> 3); // bijective XCD swizzle (256=8*32)
    const int coy = blockIdx.y;    // 128-co tile
    const int n = bx >> 6, y = bx & 63;

    // A-staging roles: pixel p (slot0) / p+32 (slot1), channel quad j
    const int ppx = t >> 3;        // 0..31
    const int j4 = (t & 7) * 4;    // channel quad within 32-ch chunk
    // B-staging roles (unchanged from round 6)
    const int bco = t >> 1;        // B row 0..127
    const int bh = t & 1;          // half of B row

    // mfma roles
    const int lane = t & 63, wv = t >> 6;
    const int wm = wv & 1, wn = wv >> 1;
    const int l15 = lane & 15, lq = lane >> 4;

    PixSt q0, q1;                  // per-slot bilinear state (tap-current)

    auto mkcoef = [&](PixSt& q, int pixel, int k, float dy, float dx) {
        const int kh = k / KS, kw = k - kh * KS;
        const float py = (float)(y + kh - PAD) + dy;
        const float pxc = (float)(pixel + kw - PAD) + dx;
        const float y0f = floorf(py), x0f = floorf(pxc);
        const int iy0 = (int)y0f, ix0 = (int)x0f;
        const int iy1 = iy0 + 1, ix1 = ix0 + 1;
        const float wy1 = py - y0f, wy0 = 1.f - wy1;
        const float wx1 = pxc - x0f, wx0 = 1.f - wx1;
        const bool vy0 = (iy0 >= 0) & (iy0 < 64), vy1 = (iy1 >= 0) & (iy1 < 64);
        const bool vx0 = (ix0 >= 0) & (ix0 < 64), vx1 = (ix1 >= 0) & (ix1 < 64);
        q.w0 = (vy0 & vx0) ? wy0 * wx0 : 0.f;
        q.w1 = (vy0 & vx1) ? wy0 * wx1 : 0.f;
        q.w2 = (vy1 & vx0) ? wy1 * wx0 : 0.f;
        q.w3 = (vy1 & vx1) ? wy1 * wx1 : 0.f;
        const int cy0 = min(max(iy0, 0), 63), cy1 = min(max(iy1, 0), 63);
        const int cx0 = min(max(ix0, 0), 63), cx1 = min(max(ix1, 0), 63);
        q.p00 = in + (size_t)(((n << 6) + cy0) * 64 + cx0) * CIN + j4;
        q.p01 = in + (size_t)(((n << 6) + cy0) * 64 + cx1) * CIN + j4;
        q.p10 = in + (size_t)(((n << 6) + cy1) * 64 + cx0) * CIN + j4;
        q.p11 = in + (size_t)(((n << 6) + cy1) * 64 + cx1) * CIN + j4;
    };

    auto oidx = [&](int k, int pixel) {
        return ((n * 2 * TAPS + 2 * k) * 64 + y) * 64 + pixel;
    };

    // prefetch registers (next chunk)
    float4 A0[4], A1[4];
    uint4 B0, B1, B2, B3;

    auto load_chunk = [&](int k, int c) {
        const int o = c * 32;
        A0[0] = *(const float4*)(q0.p00 + o);
        A0[1] = *(const float4*)(q0.p01 + o);
        A0[2] = *(const float4*)(q0.p10 + o);
        A0[3] = *(const float4*)(q0.p11 + o);
        A1[0] = *(const float4*)(q1.p00 + o);
        A1[1] = *(const float4*)(q1.p01 + o);
        A1[2] = *(const float4*)(q1.p10 + o);
        A1[3] = *(const float4*)(q1.p11 + o);
        const size_t brow = ((size_t)(k * NC + c) * COUTF + coy * 128 + bco) * 64;
        const uint4* bp = (const uint4*)(wt + brow);
        B0 = bp[bh * 2]; B1 = bp[bh * 2 + 1];     // hi half-row (32 B)
        B2 = bp[4 + bh * 2]; B3 = bp[5 + bh * 2]; // lo half-row (32 B)
    };

    auto write_chunk = [&]() {
        float v0[4], v1[4];
        v0[0] = q0.w0 * A0[0].x + q0.w1 * A0[1].x + q0.w2 * A0[2].x + q0.w3 * A0[3].x;
        v0[1] = q0.w0 * A0[0].y + q0.w1 * A0[1].y + q0.w2 * A0[2].y + q0.w3 * A0[3].y;
        v0[2] = q0.w0 * A0[0].z + q0.w1 * A0[1].z + q0.w2 * A0[2].z + q0.w3 * A0[3].z;
        v0[3] = q0.w0 * A0[0].w + q0.w1 * A0[1].w + q0.w2 * A0[2].w + q0.w3 * A0[3].w;
        v1[0] = q1.w0 * A1[0].x + q1.w1 * A1[1].x + q1.w2 * A1[2].x + q1.w3 * A1[3].x;
        v1[1] = q1.w0 * A1[0].y + q1.w1 * A1[1].y + q1.w2 * A1[2].y + q1.w3 * A1[3].y;
        v1[2] = q1.w0 * A1[0].z + q1.w1 * A1[1].z + q1.w2 * A1[2].z + q1.w3 * A1[3].z;
        v1[3] = q1.w0 * A1[0].w + q1.w1 * A1[1].w + q1.w2 * A1[2].w + q1.w3 * A1[3].w;
        f16x4 hv0, lv0, hv1, lv1;
#pragma unroll
        for (int j = 0; j < 4; ++j) {
            const _Float16 h0 = (_Float16)v0[j];
            hv0[j] = h0;
            lv0[j] = (_Float16)(v0[j] - (float)h0);
            const _Float16 h1 = (_Float16)v1[j];
            hv1[j] = h1;
            lv1[j] = (_Float16)(v1[j] - (float)h1);
        }
        *(f16x4*)&sAh[ppx * 40 + j4] = hv0;
        *(f16x4*)&sAl[ppx * 40 + j4] = lv0;
        *(f16x4*)&sAh[(ppx + 32) * 40 + j4] = hv1;
        *(f16x4*)&sAl[(ppx + 32) * 40 + j4] = lv1;
        *(uint4*)&sBh[bco * 40 + bh * 16] = B0;
        *(uint4*)&sBh[bco * 40 + bh * 16 + 8] = B1;
        *(uint4*)&sBl[bco * 40 + bh * 16] = B2;
        *(uint4*)&sBl[bco * 40 + bh * 16 + 8] = B3;
    };

    // prologue
    {
        const int o0 = oidx(0, ppx), o1 = oidx(0, ppx + 32);
        mkcoef(q0, ppx, 0, off[o0], off[o0 + 4096]);
        mkcoef(q1, ppx + 32, 0, off[o1], off[o1 + 4096]);
    }
    float dyn0 = 0.f, dxn0 = 0.f, dyn1 = 0.f, dxn1 = 0.f;
    if (TAPS > 1) {
        const int o0 = oidx(1, ppx), o1 = oidx(1, ppx + 32);
        dyn0 = off[o0]; dxn0 = off[o0 + 4096];
        dyn1 = off[o1]; dxn1 = off[o1 + 4096];
    }
    load_chunk(0, 0);

    f32x4 acc[2][4] = {};

    int k = 0, c = 0;
    for (int it = 0; it < TOTAL_IT; ++it) {
        __syncthreads();              // previous MFMA done reading LDS
        write_chunk();                // stage current chunk (regs -> LDS)
        if (it + 1 < TOTAL_IT) {
            int c2 = c + 1, k2 = k;
            if (c2 == NC) {
                c2 = 0; k2 = k + 1;
                mkcoef(q0, ppx, k2, dyn0, dxn0);
                mkcoef(q1, ppx + 32, k2, dyn1, dxn1);
                if (k2 + 1 < TAPS) {
                    const int o0 = oidx(k2 + 1, ppx), o1 = oidx(k2 + 1, ppx + 32);
                    dyn0 = off[o0]; dxn0 = off[o0 + 4096];
                    dyn1 = off[o1]; dxn1 = off[o1 + 4096];
                }
            }
            load_chunk(k2, c2);       // issue next-chunk loads BEFORE MFMA
            k = k2; c = c2;
        }
        __syncthreads();              // staged data visible

        f16x8 ah[2], al[2], bhv[4], blv[4];
#pragma unroll
        for (int mi = 0; mi < 2; ++mi) {
            const int ar = wm * 32 + mi * 16 + l15;
            ah[mi] = *(const f16x8*)&sAh[ar * 40 + lq * 8];
            al[mi] = *(const f16x8*)&sAl[ar * 40 + lq * 8];
        }
#pragma unroll
        for (int ni = 0; ni < 4; ++ni) {
            const int br = wn * 64 + ni * 16 + l15;
            bhv[ni] = *(const f16x8*)&sBh[br * 40 + lq * 8];
            blv[ni] = *(const f16x8*)&sBl[br * 40 + lq * 8];
        }
#pragma unroll
        for (int mi = 0; mi < 2; ++mi)
#pragma unroll
            for (int ni = 0; ni < 4; ++ni) {
                acc[mi][ni] = __builtin_amdgcn_mfma_f32_16x16x32_f16(ah[mi], bhv[ni], acc[mi][ni], 0, 0, 0);
                acc[mi][ni] = __builtin_amdgcn_mfma_f32_16x16x32_f16(ah[mi], blv[ni], acc[mi][ni], 0, 0, 0);
                acc[mi][ni] = __builtin_amdgcn_mfma_f32_16x16x32_f16(al[mi], bhv[ni], acc[mi][ni], 0, 0, 0);
            }
    }

    // epilogue: bias + ReLU, fp32 NHWC store
    const size_t pixbase = (size_t)bx * 64;
#pragma unroll
    for (int ni = 0; ni < 4; ++ni) {
        const int co = coy * 128 + wn * 64 + ni * 16 + l15;
        const float bv = bias[co];
#pragma unroll
        for (int mi = 0; mi < 2; ++mi) {
#pragma unroll
            for (int r = 0; r < 4; ++r) {
                const int pxl = wm * 32 + mi * 16 + lq * 4 + r;
                out[(pixbase + pxl) * COUTF + co] = fmaxf(acc[mi][ni][r] + bv, 0.f);
            }
        }
    }
}

extern "C" void kernel_launch(void* const* d_in, const int* in_sizes, int n_in,
                              void* d_out, int out_size, void* d_ws, size_t ws_size,
                              hipStream_t stream) {
    (void)in_sizes; (void)n_in; (void)out_size; (void)ws_size;
    const float* x = (const float*)d_in[0];
    const float* offs[8];
    const float* wsrc[8];
    const float* bs[8];
    for (int i = 0; i < 8; ++i) {
        offs[i] = (const float*)d_in[1 + i];
        wsrc[i] = (const float*)d_in[9 + 2 * i];
        bs[i] = (const float*)d_in[10 + 2 * i];
    }
    // workspace: bufA 32MB | bufB 16MB | wt (fp16 hi/lo) 5.25MB
    float* bufA = (float*)d_ws;
    float* bufB = (float*)((char*)d_ws + 33554432u);
    _Float16* wt = (_Float16*)((char*)d_ws + 50331648u);
    const size_t wo[8] = {0, 262144, 851968, 1146880, 1441792, 1736704, 2031616, 2326528};
    const int cins[8] = {512, 256, 128, 128, 128, 128, 128, 128};
    const int couts[8] = {256, 128, 128, 128, 128, 128, 128, 128};
    const int kks[8] = {1, 9, 9, 9, 9, 9, 9, 9};

    nchw2nhwc<<<dim3((512 / 32) * 2, 64, 4), 256, 0, stream>>>(x, bufA, 512);
    for (int i = 0; i < 8; ++i) {
        const int total = kks[i] * cins[i] * couts[i];
        prep_w<<<(total + 255) / 256, 256, 0, stream>>>(wsrc[i], wt + wo[i],
                                                        cins[i], couts[i], kks[i], total);
    }
    dconv_mfma<1, 512, 256><<<dim3(256, 2), 256, 0, stream>>>(bufA, offs[0], wt + wo[0], bs[0], bufB);
    dconv_mfma<9, 256, 128><<<dim3(256, 1), 256, 0, stream>>>(bufB, offs[1], wt + wo[1], bs[1], bufA);
    dconv_mfma<9, 128, 128><<<dim3(256, 1), 256, 0, stream>>>(bufA, offs[2], wt + wo[2], bs[2], bufB);
    dconv_mfma<9, 128, 128><<<dim3(256, 1), 256, 0, stream>>>(bufB, offs[3], wt + wo[3], bs[3], bufA);
    dconv_mfma<9, 128, 128><<<dim3(256, 1), 256, 0, stream>>>(bufA, offs[4], wt + wo[4], bs[4], bufB);
    dconv_mfma<9, 128, 128><<<dim3(256, 1), 256, 0, stream>>>(bufB, offs[5], wt + wo[5], bs[5], bufA);
    dconv_mfma<9, 128, 128><<<dim3(256, 1), 256, 0, stream>>>(bufA, offs[6], wt + wo[6], bs[6], bufB);
    dconv_mfma<9, 128, 128><<<dim3(256, 1), 256, 0, stream>>>(bufB, offs[7], wt + wo[7], bs[7], bufA);
    nhwc2nchw<<<dim3((128 / 32) * 2, 64, 4), 256, 0, stream>>>(bufA, (float*)d_out, 128);
}